// Round 2
// baseline (745.811 us; speedup 1.0000x reference)
//
#include <hip/hip_runtime.h>
#include <hip/hip_bf16.h>

#define N_NODES 50000
#define N_EDGES 800000
#define IN_F    128
#define HID     512
#define HF      128
#define MLPH    32
#define NP      8

// ---------------------------------------------------------------- CSR build
__global__ void k_deg(const int* __restrict__ dst, int* __restrict__ deg) {
    int e = blockIdx.x * 256 + threadIdx.x;
    if (e < N_EDGES) atomicAdd(&deg[dst[e]], 1);
}

// single-block scan: rowptr (exclusive, 50001), cursor (=rowptr copy), deg_inv
__global__ void k_scan(const int* __restrict__ deg, int* __restrict__ rowptr,
                       int* __restrict__ cursor, float* __restrict__ dinv) {
    __shared__ int wsum[16];
    __shared__ int carrySh;
    int t = threadIdx.x;
    int lane = t & 63, wid = t >> 6;
    if (t == 0) { carrySh = 0; rowptr[0] = 0; }
    __syncthreads();
    for (int base = 0; base < N_NODES; base += 1024) {
        int i = base + t;
        int v = (i < N_NODES) ? deg[i] : 0;
        if (i < N_NODES) dinv[i] = 1.0f / fmaxf((float)v, 1.0f);
        int x = v;
        #pragma unroll
        for (int off = 1; off < 64; off <<= 1) {
            int y = __shfl_up(x, off, 64);
            if (lane >= off) x += y;
        }
        if (lane == 63) wsum[wid] = x;
        __syncthreads();
        if (wid == 0) {
            int s = (lane < 16) ? wsum[lane] : 0;
            #pragma unroll
            for (int off = 1; off < 16; off <<= 1) {
                int y = __shfl_up(s, off, 64);
                if (lane >= off) s += y;
            }
            if (lane < 16) wsum[lane] = s;
        }
        __syncthreads();
        int waveOff = (wid == 0) ? 0 : wsum[wid - 1];
        int incl = x + waveOff + carrySh;
        if (i < N_NODES) { rowptr[i + 1] = incl; cursor[i] = incl - v; }
        __syncthreads();
        if (t == 1023) carrySh = incl;
        __syncthreads();
    }
}

__global__ void k_fill(const int* __restrict__ src, const int* __restrict__ dst,
                       int* __restrict__ cursor, int* __restrict__ col) {
    int e = blockIdx.x * 256 + threadIdx.x;
    if (e < N_EDGES) {
        int d = dst[e];
        int p = atomicAdd(&cursor[d], 1);
        col[p] = src[e];
    }
}

// --------------------------------------------------- aggregation (128-dim)
__global__ void k_agg(const float* __restrict__ y, const int* __restrict__ rowptr,
                      const int* __restrict__ col, const float* __restrict__ dinv,
                      float* __restrict__ out) {
    int n = blockIdx.x, t = threadIdx.x;
    int s = rowptr[n], e = rowptr[n + 1];
    float a0 = 0.f, a1 = 0.f, a2 = 0.f, a3 = 0.f;
    int i = s;
    for (; i + 4 <= e; i += 4) {
        int c0 = col[i], c1 = col[i + 1], c2 = col[i + 2], c3 = col[i + 3];
        a0 += y[c0 * 128 + t]; a1 += y[c1 * 128 + t];
        a2 += y[c2 * 128 + t]; a3 += y[c3 * 128 + t];
    }
    for (; i < e; ++i) a0 += y[col[i] * 128 + t];
    out[n * 128 + t] = (a0 + a1 + a2 + a3) * dinv[n];
}

// h2 = relu(z + agg(y1)*dinv + b2)
__global__ void k_aggfuse(const float* __restrict__ y1, const int* __restrict__ rowptr,
                          const int* __restrict__ col, const float* __restrict__ dinv,
                          const float* __restrict__ z, const float* __restrict__ b2,
                          float* __restrict__ h2) {
    int n = blockIdx.x, t = threadIdx.x;
    int s = rowptr[n], e = rowptr[n + 1];
    float a0 = 0.f, a1 = 0.f, a2 = 0.f, a3 = 0.f;
    int i = s;
    for (; i + 4 <= e; i += 4) {
        int c0 = col[i], c1 = col[i + 1], c2 = col[i + 2], c3 = col[i + 3];
        a0 += y1[c0 * 128 + t]; a1 += y1[c1 * 128 + t];
        a2 += y1[c2 * 128 + t]; a3 += y1[c3 * 128 + t];
    }
    for (; i < e; ++i) a0 += y1[col[i] * 128 + t];
    float agg = (a0 + a1 + a2 + a3) * dinv[n];
    h2[n * 128 + t] = fmaxf(z[n * 128 + t] + agg + b2[t], 0.f);
}

// --------------------------------------------------------------- GEMM 1
// h1 = relu([feat | agg1] @ [W1_self ; W1_neigh] + b1)   M=50000 N=512 K=256
// BM=64 BN=128 TK=16, 256 threads, 4x8 microtile
__global__ __launch_bounds__(256) void k_gemm1(
    const float* __restrict__ F, const float* __restrict__ G,
    const float* __restrict__ Wself, const float* __restrict__ Wneigh,
    const float* __restrict__ bias, float* __restrict__ C) {
    __shared__ float sA[16][68];   // k-major, padded
    __shared__ float sB[16][128];
    int t = threadIdx.x;
    int ty = t >> 4, tx = t & 15;
    int mBase = blockIdx.x * 64;
    int nBase = blockIdx.y * 128;
    float acc[4][8];
    #pragma unroll
    for (int i = 0; i < 4; ++i)
        #pragma unroll
        for (int j = 0; j < 8; ++j) acc[i][j] = 0.f;

    int ar = t >> 2;          // 0..63  (A row within tile)
    int ak = (t & 3) * 4;     // 0,4,8,12
    int br = t >> 4;          // 0..15  (B k-row)
    int bc = (t & 15) * 4;    // 0..60
    int gm = mBase + ar; if (gm >= N_NODES) gm = N_NODES - 1;

    for (int kt = 0; kt < 16; ++kt) {
        const float* Ap = (kt < 8) ? F : G;
        int kloc = (kt & 7) * 16 + ak;
        float4 av = *(const float4*)(Ap + (size_t)gm * 128 + kloc);
        int gk = kt * 16 + br;
        const float* Bp = (gk < 128) ? (Wself + (size_t)gk * 512)
                                     : (Wneigh + (size_t)(gk - 128) * 512);
        float4 bv0 = *(const float4*)(Bp + nBase + bc);
        float4 bv1 = *(const float4*)(Bp + nBase + 64 + bc);
        __syncthreads();
        sA[ak + 0][ar] = av.x; sA[ak + 1][ar] = av.y;
        sA[ak + 2][ar] = av.z; sA[ak + 3][ar] = av.w;
        *(float4*)&sB[br][bc] = bv0;
        *(float4*)&sB[br][bc + 64] = bv1;
        __syncthreads();
        #pragma unroll
        for (int k = 0; k < 16; ++k) {
            float4 a  = *(const float4*)&sA[k][ty * 4];
            float4 b0 = *(const float4*)&sB[k][tx * 4];
            float4 b1 = *(const float4*)&sB[k][tx * 4 + 64];
            float av_[4] = {a.x, a.y, a.z, a.w};
            float bv_[8] = {b0.x, b0.y, b0.z, b0.w, b1.x, b1.y, b1.z, b1.w};
            #pragma unroll
            for (int ii = 0; ii < 4; ++ii)
                #pragma unroll
                for (int jj = 0; jj < 8; ++jj)
                    acc[ii][jj] += av_[ii] * bv_[jj];
        }
    }
    float4 bb0 = *(const float4*)(bias + nBase + tx * 4);
    float4 bb1 = *(const float4*)(bias + nBase + tx * 4 + 64);
    float bb[8] = {bb0.x, bb0.y, bb0.z, bb0.w, bb1.x, bb1.y, bb1.z, bb1.w};
    #pragma unroll
    for (int i = 0; i < 4; ++i) {
        int gm2 = mBase + ty * 4 + i;
        if (gm2 < N_NODES) {
            float4 o0, o1;
            o0.x = fmaxf(acc[i][0] + bb[0], 0.f); o0.y = fmaxf(acc[i][1] + bb[1], 0.f);
            o0.z = fmaxf(acc[i][2] + bb[2], 0.f); o0.w = fmaxf(acc[i][3] + bb[3], 0.f);
            o1.x = fmaxf(acc[i][4] + bb[4], 0.f); o1.y = fmaxf(acc[i][5] + bb[5], 0.f);
            o1.z = fmaxf(acc[i][6] + bb[6], 0.f); o1.w = fmaxf(acc[i][7] + bb[7], 0.f);
            *(float4*)(C + (size_t)gm2 * 512 + nBase + tx * 4) = o0;
            *(float4*)(C + (size_t)gm2 * 512 + nBase + tx * 4 + 64) = o1;
        }
    }
}

// --------------------------------------------------------------- GEMM 2
// [z | y1] = h1 @ [W2_self | W2_neigh]    M=50000 N=128(each) K=512
__global__ __launch_bounds__(256) void k_gemm2(
    const float* __restrict__ A, const float* __restrict__ Wself,
    const float* __restrict__ Wneigh, float* __restrict__ Z,
    float* __restrict__ Y1) {
    __shared__ float sA[16][68];
    __shared__ float sB[16][128];
    int t = threadIdx.x;
    int ty = t >> 4, tx = t & 15;
    int mBase = blockIdx.x * 64;
    const float* Bmat = (blockIdx.y == 0) ? Wself : Wneigh;
    float* Omat = (blockIdx.y == 0) ? Z : Y1;
    float acc[4][8];
    #pragma unroll
    for (int i = 0; i < 4; ++i)
        #pragma unroll
        for (int j = 0; j < 8; ++j) acc[i][j] = 0.f;

    int ar = t >> 2;
    int ak = (t & 3) * 4;
    int br = t >> 4;
    int bc = (t & 15) * 4;
    int gm = mBase + ar; if (gm >= N_NODES) gm = N_NODES - 1;

    for (int kt = 0; kt < 32; ++kt) {
        float4 av = *(const float4*)(A + (size_t)gm * 512 + kt * 16 + ak);
        int gk = kt * 16 + br;
        float4 bv0 = *(const float4*)(Bmat + (size_t)gk * 128 + bc);
        float4 bv1 = *(const float4*)(Bmat + (size_t)gk * 128 + bc + 64);
        __syncthreads();
        sA[ak + 0][ar] = av.x; sA[ak + 1][ar] = av.y;
        sA[ak + 2][ar] = av.z; sA[ak + 3][ar] = av.w;
        *(float4*)&sB[br][bc] = bv0;
        *(float4*)&sB[br][bc + 64] = bv1;
        __syncthreads();
        #pragma unroll
        for (int k = 0; k < 16; ++k) {
            float4 a  = *(const float4*)&sA[k][ty * 4];
            float4 b0 = *(const float4*)&sB[k][tx * 4];
            float4 b1 = *(const float4*)&sB[k][tx * 4 + 64];
            float av_[4] = {a.x, a.y, a.z, a.w};
            float bv_[8] = {b0.x, b0.y, b0.z, b0.w, b1.x, b1.y, b1.z, b1.w};
            #pragma unroll
            for (int ii = 0; ii < 4; ++ii)
                #pragma unroll
                for (int jj = 0; jj < 8; ++jj)
                    acc[ii][jj] += av_[ii] * bv_[jj];
        }
    }
    #pragma unroll
    for (int i = 0; i < 4; ++i) {
        int gm2 = mBase + ty * 4 + i;
        if (gm2 < N_NODES) {
            float4 o0 = {acc[i][0], acc[i][1], acc[i][2], acc[i][3]};
            float4 o1 = {acc[i][4], acc[i][5], acc[i][6], acc[i][7]};
            *(float4*)(Omat + (size_t)gm2 * 128 + tx * 4) = o0;
            *(float4*)(Omat + (size_t)gm2 * 128 + tx * 4 + 64) = o1;
        }
    }
}

// ------------------------------------------------------------- MLP head
// x = relu(h2 @ Wp1 + bp1); logits = x @ Wp2 + bp2; softmax -> out (FP32)
__global__ __launch_bounds__(256) void k_mlp(
    const float* __restrict__ h2, const float* __restrict__ Wp1,
    const float* __restrict__ bp1, const float* __restrict__ Wp2,
    const float* __restrict__ bp2, float* __restrict__ out) {
    __shared__ float xsh[4][32];
    int t = threadIdx.x, lane = t & 63, wv = t >> 6;
    int n = blockIdx.x * 4 + wv;          // grid is exactly 12500 -> n < 50000
    int j = lane & 31, half = lane >> 5;
    const float* hrow = h2 + (size_t)n * 128 + half * 64;
    float acc = 0.f;
    #pragma unroll 8
    for (int k = 0; k < 64; ++k)
        acc += hrow[k] * Wp1[(half * 64 + k) * 32 + j];
    acc += __shfl_xor(acc, 32, 64);
    acc += bp1[j];
    if (half == 0) xsh[wv][j] = fmaxf(acc, 0.f);
    __syncthreads();
    float lg = 0.f;
    if (lane < 8) {
        lg = bp2[lane];
        #pragma unroll
        for (int jj = 0; jj < 32; ++jj)
            lg += xsh[wv][jj] * Wp2[jj * 8 + lane];
    }
    float mx = lg;
    mx = fmaxf(mx, __shfl_xor(mx, 1, 64));
    mx = fmaxf(mx, __shfl_xor(mx, 2, 64));
    mx = fmaxf(mx, __shfl_xor(mx, 4, 64));
    float ev = expf(lg - mx);
    float sm = ev;
    sm += __shfl_xor(sm, 1, 64);
    sm += __shfl_xor(sm, 2, 64);
    sm += __shfl_xor(sm, 4, 64);
    if (lane < 8) out[(size_t)n * 8 + lane] = ev / sm;
}

// ---------------------------------------------------------------- launch
extern "C" void kernel_launch(void* const* d_in, const int* in_sizes, int n_in,
                              void* d_out, int out_size, void* d_ws, size_t ws_size,
                              hipStream_t stream) {
    const float* feat   = (const float*)d_in[0];
    const int*   src    = (const int*)d_in[1];
    const int*   dst    = (const int*)d_in[2];
    const float* W1s    = (const float*)d_in[3];
    const float* W1n    = (const float*)d_in[4];
    const float* b1     = (const float*)d_in[5];
    const float* W2s    = (const float*)d_in[6];
    const float* W2n    = (const float*)d_in[7];
    const float* b2     = (const float*)d_in[8];
    const float* Wp1    = (const float*)d_in[9];
    const float* bp1    = (const float*)d_in[10];
    const float* Wp2    = (const float*)d_in[11];
    const float* bp2    = (const float*)d_in[12];
    float* out = (float*)d_out;

    char* w = (char*)d_ws;
    size_t off = 0;
    auto alloc = [&](size_t bytes) { char* p = w + off; off += (bytes + 255) & ~(size_t)255; return p; };
    int*   deg    = (int*)alloc(N_NODES * 4);
    int*   rowptr = (int*)alloc((N_NODES + 1) * 4);
    int*   cursor = (int*)alloc(N_NODES * 4);
    int*   col    = (int*)alloc(N_EDGES * 4);
    float* dinv   = (float*)alloc(N_NODES * 4);
    float* agg1z  = (float*)alloc((size_t)N_NODES * 128 * 4);  // agg1, later z
    float* y1     = (float*)alloc((size_t)N_NODES * 128 * 4);
    float* h1     = (float*)alloc((size_t)N_NODES * 512 * 4);  // later h2 (first 128 cols)
    float* h2     = h1;

    hipMemsetAsync(deg, 0, N_NODES * 4, stream);
    k_deg<<<(N_EDGES + 255) / 256, 256, 0, stream>>>(dst, deg);
    k_scan<<<1, 1024, 0, stream>>>(deg, rowptr, cursor, dinv);
    k_fill<<<(N_EDGES + 255) / 256, 256, 0, stream>>>(src, dst, cursor, col);
    // layer 1: aggregate features (128-dim) then fused GEMM
    k_agg<<<N_NODES, 128, 0, stream>>>(feat, rowptr, col, dinv, agg1z);
    dim3 g1((N_NODES + 63) / 64, 4);
    k_gemm1<<<g1, 256, 0, stream>>>(feat, agg1z, W1s, W1n, b1, h1);
    // layer 2: project first (512->128 both halves), then aggregate y1
    dim3 g2((N_NODES + 63) / 64, 2);
    k_gemm2<<<g2, 256, 0, stream>>>(h1, W2s, W2n, agg1z /*z*/, y1);
    k_aggfuse<<<N_NODES, 128, 0, stream>>>(y1, rowptr, col, dinv, agg1z, b2, h2);
    // MLP head + softmax
    k_mlp<<<N_NODES / 4, 256, 0, stream>>>(h2, Wp1, bp1, Wp2, bp2, out);
}

// Round 3
// 493.940 us; speedup vs baseline: 1.5099x; 1.5099x over previous
//
#include <hip/hip_runtime.h>
#include <hip/hip_bf16.h>

#define N_NODES 50000
#define N_EDGES 800000

typedef short  short8  __attribute__((ext_vector_type(8)));
typedef float  floatx4 __attribute__((ext_vector_type(4)));

__device__ __forceinline__ short f2bf(float f) {
    union { __hip_bfloat16 h; short s; } u;
    u.h = __float2bfloat16(f);
    return u.s;
}

__device__ __forceinline__ void gld_lds16(const short* g, short* l) {
    __builtin_amdgcn_global_load_lds(
        (const __attribute__((address_space(1))) int*)g,
        (__attribute__((address_space(3))) int*)l, 16, 0, 0);
}

// ---------------------------------------------------------------- CSR build
__global__ void k_deg(const int* __restrict__ dst, int* __restrict__ deg) {
    int e = blockIdx.x * 256 + threadIdx.x;
    if (e < N_EDGES) atomicAdd(&deg[dst[e]], 1);
}

__global__ void k_scan(const int* __restrict__ deg, int* __restrict__ rowptr,
                       int* __restrict__ cursor, float* __restrict__ dinv) {
    __shared__ int wsum[16];
    __shared__ int carrySh;
    int t = threadIdx.x;
    int lane = t & 63, wid = t >> 6;
    if (t == 0) { carrySh = 0; rowptr[0] = 0; }
    __syncthreads();
    for (int base = 0; base < N_NODES; base += 1024) {
        int i = base + t;
        int v = (i < N_NODES) ? deg[i] : 0;
        if (i < N_NODES) dinv[i] = 1.0f / fmaxf((float)v, 1.0f);
        int x = v;
        #pragma unroll
        for (int off = 1; off < 64; off <<= 1) {
            int y = __shfl_up(x, off, 64);
            if (lane >= off) x += y;
        }
        if (lane == 63) wsum[wid] = x;
        __syncthreads();
        if (wid == 0) {
            int s = (lane < 16) ? wsum[lane] : 0;
            #pragma unroll
            for (int off = 1; off < 16; off <<= 1) {
                int y = __shfl_up(s, off, 64);
                if (lane >= off) s += y;
            }
            if (lane < 16) wsum[lane] = s;
        }
        __syncthreads();
        int waveOff = (wid == 0) ? 0 : wsum[wid - 1];
        int incl = x + waveOff + carrySh;
        if (i < N_NODES) { rowptr[i + 1] = incl; cursor[i] = incl - v; }
        __syncthreads();
        if (t == 1023) carrySh = incl;
        __syncthreads();
    }
}

__global__ void k_fill(const int* __restrict__ src, const int* __restrict__ dst,
                       int* __restrict__ cursor, int* __restrict__ col) {
    int e = blockIdx.x * 256 + threadIdx.x;
    if (e < N_EDGES) {
        int d = dst[e];
        int p = atomicAdd(&cursor[d], 1);
        col[p] = src[e];
    }
}

// ------------------------------------------------------ bf16 conversions
// Abf[n][0:128] = bf16(feat[n])   (Abf is 50000 x 256)
__global__ void k_cvt_feat(const float* __restrict__ feat, short* __restrict__ Abf) {
    int idx = blockIdx.x * 256 + threadIdx.x;
    if (idx >= N_NODES * 32) return;
    int n = idx >> 5, c = (idx & 31) * 4;
    float4 v = *(const float4*)(feat + (size_t)n * 128 + c);
    *(short4*)(Abf + (size_t)n * 256 + c) =
        make_short4(f2bf(v.x), f2bf(v.y), f2bf(v.z), f2bf(v.w));
}

// W1T[512][256] = [W1s;W1n]^T (bf16);  W2T[256][512] = [W2s|W2n]^T (bf16)
__global__ void k_cvt_w(const float* __restrict__ W1s, const float* __restrict__ W1n,
                        const float* __restrict__ W2s, const float* __restrict__ W2n,
                        short* __restrict__ W1T, short* __restrict__ W2T) {
    int idx = blockIdx.x * 256 + threadIdx.x;
    if (idx < 512 * 256) {
        int n = idx >> 8, k = idx & 255;
        float v = (k < 128) ? W1s[(size_t)k * 512 + n]
                            : W1n[(size_t)(k - 128) * 512 + n];
        W1T[idx] = f2bf(v);
    } else {
        int j = idx - 512 * 256;   // 256*512 entries
        int n = j >> 9, k = j & 511;
        float v = (n < 128) ? W2s[(size_t)k * 128 + n]
                            : W2n[(size_t)k * 128 + (n - 128)];
        W2T[j] = f2bf(v);
    }
}

// ---------------------------------------------- aggregation (fp32 gather)
// writes bf16 mean-agg into Abf cols 128..255
__global__ void k_agg(const float* __restrict__ y, const int* __restrict__ rowptr,
                      const int* __restrict__ col, const float* __restrict__ dinv,
                      short* __restrict__ Abf) {
    int n = blockIdx.x, t = threadIdx.x;
    int s = rowptr[n], e = rowptr[n + 1];
    float a0 = 0.f, a1 = 0.f, a2 = 0.f, a3 = 0.f;
    int i = s;
    for (; i + 4 <= e; i += 4) {
        int c0 = col[i], c1 = col[i + 1], c2 = col[i + 2], c3 = col[i + 3];
        a0 += y[(size_t)c0 * 128 + t]; a1 += y[(size_t)c1 * 128 + t];
        a2 += y[(size_t)c2 * 128 + t]; a3 += y[(size_t)c3 * 128 + t];
    }
    for (; i < e; ++i) a0 += y[(size_t)col[i] * 128 + t];
    Abf[(size_t)n * 256 + 128 + t] = f2bf((a0 + a1 + a2 + a3) * dinv[n]);
}

// h2 = relu(z + agg(y1)*dinv + b2)
__global__ void k_aggfuse(const float* __restrict__ y1, const int* __restrict__ rowptr,
                          const int* __restrict__ col, const float* __restrict__ dinv,
                          const float* __restrict__ z, const float* __restrict__ b2,
                          float* __restrict__ h2) {
    int n = blockIdx.x, t = threadIdx.x;
    int s = rowptr[n], e = rowptr[n + 1];
    float a0 = 0.f, a1 = 0.f, a2 = 0.f, a3 = 0.f;
    int i = s;
    for (; i + 4 <= e; i += 4) {
        int c0 = col[i], c1 = col[i + 1], c2 = col[i + 2], c3 = col[i + 3];
        a0 += y1[(size_t)c0 * 128 + t]; a1 += y1[(size_t)c1 * 128 + t];
        a2 += y1[(size_t)c2 * 128 + t]; a3 += y1[(size_t)c3 * 128 + t];
    }
    for (; i < e; ++i) a0 += y1[(size_t)col[i] * 128 + t];
    float agg = (a0 + a1 + a2 + a3) * dinv[n];
    h2[(size_t)n * 128 + t] = fmaxf(z[(size_t)n * 128 + t] + agg + b2[t], 0.f);
}

// ------------------------------------------------------- MFMA bf16 GEMM
// C = A(MxK bf16) x BT^T(BT is NxK bf16).  128x128 tile, BK=32, 4 waves 2x2.
// EPI1: Obf = bf16(relu(C + bias)), ldc=N.  !EPI1: N==256, cols<128 -> Of0,
// cols>=128 -> Of1, both 50000x128 fp32.
template<int K, int N, bool EPI1>
__global__ __launch_bounds__(256) void k_gemm_mfma(
    const short* __restrict__ A, const short* __restrict__ BT,
    const float* __restrict__ bias, short* __restrict__ Obf,
    float* __restrict__ Of0, float* __restrict__ Of1) {
    __shared__ short sA[128 * 32];
    __shared__ short sB[128 * 32];
    const int t = threadIdx.x;
    const int lane = t & 63;
    const int w = t >> 6;
    const int mBase = blockIdx.x * 128;
    const int nBase = blockIdx.y * 128;
    const int mOff = (w & 1) * 64;
    const int nOff = (w >> 1) * 64;

    floatx4 zero4 = {0.f, 0.f, 0.f, 0.f};
    floatx4 acc[4][4];
    #pragma unroll
    for (int i = 0; i < 4; ++i)
        #pragma unroll
        for (int j = 0; j < 4; ++j) acc[i][j] = zero4;

    // staging geometry: 16 rows x 32 bf16 per wave-issue; LDS chunk c of row r
    // holds global chunk c ^ ((r>>1)&3)  (bank-spread swizzle)
    const int rL = lane >> 2;                                   // 0..15
    const int cg = (((lane & 3) ^ ((lane >> 3) & 3))) * 8;      // swizzled global chunk
    const int rA = w * 32 + rL;
    const long gA0 = (long)min(mBase + rA,      N_NODES - 1) * K + cg;
    const long gA1 = (long)min(mBase + rA + 16, N_NODES - 1) * K + cg;
    const long gB0 = (long)(nBase + rA)      * K + cg;
    const long gB1 = (long)(nBase + rA + 16) * K + cg;
    short* lA0 = sA + (w * 32) * 32;
    short* lA1 = sA + (w * 32 + 16) * 32;
    short* lB0 = sB + (w * 32) * 32;
    short* lB1 = sB + (w * 32 + 16) * 32;

    const int fr = lane & 15;
    const int csel = (((lane >> 4) ^ ((lane >> 1) & 3))) * 8;

    for (int kt = 0; kt < K / 32; ++kt) {
        const int k0 = kt * 32;
        __syncthreads();
        gld_lds16(A + gA0 + k0, lA0);
        gld_lds16(A + gA1 + k0, lA1);
        gld_lds16(BT + gB0 + k0, lB0);
        gld_lds16(BT + gB1 + k0, lB1);
        __syncthreads();
        short8 af[4], bf[4];
        #pragma unroll
        for (int i = 0; i < 4; ++i) {
            af[i] = *(const short8*)(sA + (mOff + i * 16 + fr) * 32 + csel);
            bf[i] = *(const short8*)(sB + (nOff + i * 16 + fr) * 32 + csel);
        }
        #pragma unroll
        for (int mi = 0; mi < 4; ++mi)
            #pragma unroll
            for (int ni = 0; ni < 4; ++ni)
                acc[mi][ni] = __builtin_amdgcn_mfma_f32_16x16x32_bf16(
                    af[mi], bf[ni], acc[mi][ni], 0, 0, 0);
    }

    // epilogue: D col = lane&15, row = (lane>>4)*4 + reg
    const int cn = lane & 15;
    const int cm = (lane >> 4) * 4;
    #pragma unroll
    for (int ni = 0; ni < 4; ++ni) {
        const int n = nBase + nOff + ni * 16 + cn;
        float bv = 0.f;
        if constexpr (EPI1) bv = bias[n];
        #pragma unroll
        for (int mi = 0; mi < 4; ++mi) {
            #pragma unroll
            for (int r = 0; r < 4; ++r) {
                const int m = mBase + mOff + mi * 16 + cm + r;
                if (m < N_NODES) {
                    if constexpr (EPI1) {
                        Obf[(size_t)m * N + n] = f2bf(fmaxf(acc[mi][ni][r] + bv, 0.f));
                    } else {
                        float* Op = (n < 128) ? Of0 : Of1;
                        Op[(size_t)m * 128 + (n & 127)] = acc[mi][ni][r];
                    }
                }
            }
        }
    }
}

// ------------------------------------------------------------- MLP head
__global__ __launch_bounds__(256) void k_mlp(
    const float* __restrict__ h2, const float* __restrict__ Wp1,
    const float* __restrict__ bp1, const float* __restrict__ Wp2,
    const float* __restrict__ bp2, float* __restrict__ out) {
    __shared__ float xsh[4][32];
    int t = threadIdx.x, lane = t & 63, wv = t >> 6;
    int n = blockIdx.x * 4 + wv;
    int j = lane & 31, half = lane >> 5;
    const float* hrow = h2 + (size_t)n * 128 + half * 64;
    float acc = 0.f;
    #pragma unroll 8
    for (int k = 0; k < 64; ++k)
        acc += hrow[k] * Wp1[(half * 64 + k) * 32 + j];
    acc += __shfl_xor(acc, 32, 64);
    acc += bp1[j];
    if (half == 0) xsh[wv][j] = fmaxf(acc, 0.f);
    __syncthreads();
    float lg = 0.f;
    if (lane < 8) {
        lg = bp2[lane];
        #pragma unroll
        for (int jj = 0; jj < 32; ++jj)
            lg += xsh[wv][jj] * Wp2[jj * 8 + lane];
    }
    float mx = lg;
    mx = fmaxf(mx, __shfl_xor(mx, 1, 64));
    mx = fmaxf(mx, __shfl_xor(mx, 2, 64));
    mx = fmaxf(mx, __shfl_xor(mx, 4, 64));
    float ev = expf(lg - mx);
    float sm = ev;
    sm += __shfl_xor(sm, 1, 64);
    sm += __shfl_xor(sm, 2, 64);
    sm += __shfl_xor(sm, 4, 64);
    if (lane < 8) out[(size_t)n * 8 + lane] = ev / sm;
}

// ---------------------------------------------------------------- launch
extern "C" void kernel_launch(void* const* d_in, const int* in_sizes, int n_in,
                              void* d_out, int out_size, void* d_ws, size_t ws_size,
                              hipStream_t stream) {
    const float* feat   = (const float*)d_in[0];
    const int*   src    = (const int*)d_in[1];
    const int*   dst    = (const int*)d_in[2];
    const float* W1s    = (const float*)d_in[3];
    const float* W1n    = (const float*)d_in[4];
    const float* b1     = (const float*)d_in[5];
    const float* W2s    = (const float*)d_in[6];
    const float* W2n    = (const float*)d_in[7];
    const float* b2     = (const float*)d_in[8];
    const float* Wp1    = (const float*)d_in[9];
    const float* bp1    = (const float*)d_in[10];
    const float* Wp2    = (const float*)d_in[11];
    const float* bp2    = (const float*)d_in[12];
    float* out = (float*)d_out;

    char* w = (char*)d_ws;
    size_t off = 0;
    auto alloc = [&](size_t bytes) { char* p = w + off; off += (bytes + 255) & ~(size_t)255; return p; };
    int*   deg    = (int*)alloc(N_NODES * 4);
    int*   rowptr = (int*)alloc((N_NODES + 1) * 4);
    int*   cursor = (int*)alloc(N_NODES * 4);
    int*   col    = (int*)alloc(N_EDGES * 4);
    float* dinv   = (float*)alloc(N_NODES * 4);
    short* Abf    = (short*)alloc((size_t)N_NODES * 256 * 2);   // [feat|agg1] bf16; later h2 fp32
    short* W1T    = (short*)alloc((size_t)512 * 256 * 2);
    short* W2T    = (short*)alloc((size_t)256 * 512 * 2);
    short* h1bf   = (short*)alloc((size_t)N_NODES * 512 * 2);
    float* z      = (float*)alloc((size_t)N_NODES * 128 * 4);
    float* y1     = (float*)alloc((size_t)N_NODES * 128 * 4);
    float* h2     = (float*)Abf;   // alias: Abf dead after GEMM1

    hipMemsetAsync(deg, 0, N_NODES * 4, stream);
    k_deg<<<N_EDGES / 256, 256, 0, stream>>>(dst, deg);
    k_scan<<<1, 1024, 0, stream>>>(deg, rowptr, cursor, dinv);
    k_fill<<<N_EDGES / 256, 256, 0, stream>>>(src, dst, cursor, col);
    k_cvt_feat<<<(N_NODES * 32 + 255) / 256, 256, 0, stream>>>(feat, Abf);
    k_cvt_w<<<(512 * 256 + 256 * 512) / 256, 256, 0, stream>>>(W1s, W1n, W2s, W2n, W1T, W2T);
    k_agg<<<N_NODES, 128, 0, stream>>>(feat, rowptr, col, dinv, Abf);
    dim3 g1((N_NODES + 127) / 128, 4);
    k_gemm_mfma<256, 512, true><<<g1, 256, 0, stream>>>(Abf, W1T, b1, h1bf, nullptr, nullptr);
    dim3 g2((N_NODES + 127) / 128, 2);
    k_gemm_mfma<512, 256, false><<<g2, 256, 0, stream>>>(h1bf, W2T, nullptr, nullptr, z, y1);
    k_aggfuse<<<N_NODES, 128, 0, stream>>>(y1, rowptr, col, dinv, z, b2, h2);
    k_mlp<<<N_NODES / 4, 256, 0, stream>>>(h2, Wp1, bp1, Wp2, bp2, out);
}

// Round 4
// 436.154 us; speedup vs baseline: 1.7100x; 1.1325x over previous
//
#include <hip/hip_runtime.h>
#include <hip/hip_bf16.h>

#define N_NODES 50000
#define N_EDGES 800000

typedef short  short8  __attribute__((ext_vector_type(8)));
typedef float  floatx4 __attribute__((ext_vector_type(4)));

__device__ __forceinline__ short f2bf(float f) {
    union { __hip_bfloat16 h; short s; } u;
    u.h = __float2bfloat16(f);
    return u.s;
}
__device__ __forceinline__ float bf2f(short s) {
    union { float f; unsigned u; } u;
    u.u = ((unsigned)(unsigned short)s) << 16;
    return u.f;
}

__device__ __forceinline__ void gld_lds16(const short* g, short* l) {
    __builtin_amdgcn_global_load_lds(
        (const __attribute__((address_space(1))) int*)g,
        (__attribute__((address_space(3))) int*)l, 16, 0, 0);
}

// ---------------------------------------------------------------- CSR build
__global__ void k_deg(const int* __restrict__ dst, int* __restrict__ deg) {
    int e = blockIdx.x * 256 + threadIdx.x;
    if (e < N_EDGES) atomicAdd(&deg[dst[e]], 1);
}

__global__ void k_scan(const int* __restrict__ deg, int* __restrict__ rowptr,
                       int* __restrict__ cursor, float* __restrict__ dinv) {
    __shared__ int wsum[16];
    __shared__ int carrySh;
    int t = threadIdx.x;
    int lane = t & 63, wid = t >> 6;
    if (t == 0) { carrySh = 0; rowptr[0] = 0; }
    __syncthreads();
    for (int base = 0; base < N_NODES; base += 1024) {
        int i = base + t;
        int v = (i < N_NODES) ? deg[i] : 0;
        if (i < N_NODES) dinv[i] = 1.0f / fmaxf((float)v, 1.0f);
        int x = v;
        #pragma unroll
        for (int off = 1; off < 64; off <<= 1) {
            int y = __shfl_up(x, off, 64);
            if (lane >= off) x += y;
        }
        if (lane == 63) wsum[wid] = x;
        __syncthreads();
        if (wid == 0) {
            int s = (lane < 16) ? wsum[lane] : 0;
            #pragma unroll
            for (int off = 1; off < 16; off <<= 1) {
                int y = __shfl_up(s, off, 64);
                if (lane >= off) s += y;
            }
            if (lane < 16) wsum[lane] = s;
        }
        __syncthreads();
        int waveOff = (wid == 0) ? 0 : wsum[wid - 1];
        int incl = x + waveOff + carrySh;
        if (i < N_NODES) { rowptr[i + 1] = incl; cursor[i] = incl - v; }
        __syncthreads();
        if (t == 1023) carrySh = incl;
        __syncthreads();
    }
}

__global__ void k_fill(const int* __restrict__ src, const int* __restrict__ dst,
                       int* __restrict__ cursor, int* __restrict__ col) {
    int e = blockIdx.x * 256 + threadIdx.x;
    if (e < N_EDGES) {
        int d = dst[e];
        int p = atomicAdd(&cursor[d], 1);
        col[p] = src[e];
    }
}

// ------------------------------------------------------ bf16 conversions
// Abf[n][0:128] = bf16(feat[n])   (Abf is 50000 x 256)
__global__ void k_cvt_feat(const float* __restrict__ feat, short* __restrict__ Abf) {
    int idx = blockIdx.x * 256 + threadIdx.x;
    if (idx >= N_NODES * 32) return;
    int n = idx >> 5, c = (idx & 31) * 4;
    float4 v = *(const float4*)(feat + (size_t)n * 128 + c);
    *(short4*)(Abf + (size_t)n * 256 + c) =
        make_short4(f2bf(v.x), f2bf(v.y), f2bf(v.z), f2bf(v.w));
}

// W1T[512][256] = [W1s;W1n]^T (bf16);  W2T[256][512] = [W2s|W2n]^T (bf16)
__global__ void k_cvt_w(const float* __restrict__ W1s, const float* __restrict__ W1n,
                        const float* __restrict__ W2s, const float* __restrict__ W2n,
                        short* __restrict__ W1T, short* __restrict__ W2T) {
    int idx = blockIdx.x * 256 + threadIdx.x;
    if (idx < 512 * 256) {
        int n = idx >> 8, k = idx & 255;
        float v = (k < 128) ? W1s[(size_t)k * 512 + n]
                            : W1n[(size_t)(k - 128) * 512 + n];
        W1T[idx] = f2bf(v);
    } else {
        int j = idx - 512 * 256;   // 256*512 entries
        int n = j >> 9, k = j & 511;
        float v = (n < 128) ? W2s[(size_t)k * 128 + n]
                            : W2n[(size_t)k * 128 + (n - 128)];
        W2T[j] = f2bf(v);
    }
}

// ---------------------------------------------- aggregation 1 (bf16 gather)
// mean of bf16 feat rows (Abf cols 0..127) -> bf16 into Abf cols 128..255
__global__ __launch_bounds__(128) void k_agg(
    const short* __restrict__ Abf_ro, const int* __restrict__ rowptr,
    const int* __restrict__ col, const float* __restrict__ dinv,
    short* __restrict__ Abf) {
    int n = blockIdx.x, t = threadIdx.x;
    int s = rowptr[n], e = rowptr[n + 1];
    float a0 = 0.f, a1 = 0.f, a2 = 0.f, a3 = 0.f;
    int i = s;
    for (; i + 4 <= e; i += 4) {
        int c0 = col[i], c1 = col[i + 1], c2 = col[i + 2], c3 = col[i + 3];
        a0 += bf2f(Abf_ro[(size_t)c0 * 256 + t]);
        a1 += bf2f(Abf_ro[(size_t)c1 * 256 + t]);
        a2 += bf2f(Abf_ro[(size_t)c2 * 256 + t]);
        a3 += bf2f(Abf_ro[(size_t)c3 * 256 + t]);
    }
    for (; i < e; ++i) a0 += bf2f(Abf_ro[(size_t)col[i] * 256 + t]);
    Abf[(size_t)n * 256 + 128 + t] = f2bf((a0 + a1 + a2 + a3) * dinv[n]);
}

// --------------------- aggregation 2 + bias/relu + MLP + softmax (fused)
// h2 = relu(z + mean(y1bf)*1 + b2);  x = relu(h2@Wp1+bp1);
// logits = x@Wp2+bp2; out = softmax(logits)
__global__ __launch_bounds__(128) void k_aggmlp(
    const short* __restrict__ y1bf, const int* __restrict__ rowptr,
    const int* __restrict__ col, const float* __restrict__ dinv,
    const float* __restrict__ z, const float* __restrict__ b2,
    const float* __restrict__ Wp1, const float* __restrict__ bp1,
    const float* __restrict__ Wp2, const float* __restrict__ bp2,
    float* __restrict__ out) {
    __shared__ float h2sh[128];
    __shared__ float par[4][32];
    __shared__ float xsh[32];
    int n = blockIdx.x, t = threadIdx.x;
    int s = rowptr[n], e = rowptr[n + 1];
    float a0 = 0.f, a1 = 0.f, a2 = 0.f, a3 = 0.f;
    int i = s;
    for (; i + 4 <= e; i += 4) {
        int c0 = col[i], c1 = col[i + 1], c2 = col[i + 2], c3 = col[i + 3];
        a0 += bf2f(y1bf[(size_t)c0 * 128 + t]);
        a1 += bf2f(y1bf[(size_t)c1 * 128 + t]);
        a2 += bf2f(y1bf[(size_t)c2 * 128 + t]);
        a3 += bf2f(y1bf[(size_t)c3 * 128 + t]);
    }
    for (; i < e; ++i) a0 += bf2f(y1bf[(size_t)col[i] * 128 + t]);
    float agg = (a0 + a1 + a2 + a3) * dinv[n];
    float h2v = fmaxf(z[(size_t)n * 128 + t] + agg + b2[t], 0.f);
    h2sh[t] = h2v;
    __syncthreads();
    // x = relu(h2 @ Wp1 + bp1): thread t -> j=t&31, k-chunk kc=t>>5
    int j = t & 31, kc = t >> 5;
    float p = 0.f;
    #pragma unroll
    for (int k2 = 0; k2 < 32; ++k2) {
        int k = kc * 32 + k2;
        p += h2sh[k] * Wp1[k * 32 + j];
    }
    par[kc][j] = p;
    __syncthreads();
    if (t < 32)
        xsh[t] = fmaxf(par[0][t] + par[1][t] + par[2][t] + par[3][t] + bp1[t], 0.f);
    __syncthreads();
    if (t < 8) {
        float lg = bp2[t];
        #pragma unroll
        for (int jj = 0; jj < 32; ++jj)
            lg += xsh[jj] * Wp2[jj * 8 + t];
        float mx = lg;
        mx = fmaxf(mx, __shfl_xor(mx, 1, 64));
        mx = fmaxf(mx, __shfl_xor(mx, 2, 64));
        mx = fmaxf(mx, __shfl_xor(mx, 4, 64));
        float ev = expf(lg - mx);
        float sm = ev;
        sm += __shfl_xor(sm, 1, 64);
        sm += __shfl_xor(sm, 2, 64);
        sm += __shfl_xor(sm, 4, 64);
        out[(size_t)n * 8 + t] = ev / sm;
    }
}

// ------------------------------------------------------- MFMA bf16 GEMM
// C = A(MxK bf16) x BT^T(BT is NxK bf16).  128x128 tile, BK=32, 4 waves 2x2.
// EPI1: Obf = bf16(relu(C + bias)), ldc=N (GEMM1 -> h1bf).
// !EPI1: N==256; cols<128 -> Of0 fp32 (z), cols>=128 -> Obf bf16 (y1bf).
template<int K, int N, bool EPI1>
__global__ __launch_bounds__(256) void k_gemm_mfma(
    const short* __restrict__ A, const short* __restrict__ BT,
    const float* __restrict__ bias, short* __restrict__ Obf,
    float* __restrict__ Of0) {
    __shared__ short sA[128 * 32];
    __shared__ short sB[128 * 32];
    const int t = threadIdx.x;
    const int lane = t & 63;
    const int w = t >> 6;
    const int mBase = blockIdx.x * 128;
    const int nBase = blockIdx.y * 128;
    const int mOff = (w & 1) * 64;
    const int nOff = (w >> 1) * 64;

    floatx4 zero4 = {0.f, 0.f, 0.f, 0.f};
    floatx4 acc[4][4];
    #pragma unroll
    for (int i = 0; i < 4; ++i)
        #pragma unroll
        for (int j = 0; j < 4; ++j) acc[i][j] = zero4;

    const int rL = lane >> 2;                                   // 0..15
    const int cg = (((lane & 3) ^ ((lane >> 3) & 3))) * 8;      // swizzled chunk
    const int rA = w * 32 + rL;
    const long gA0 = (long)min(mBase + rA,      N_NODES - 1) * K + cg;
    const long gA1 = (long)min(mBase + rA + 16, N_NODES - 1) * K + cg;
    const long gB0 = (long)(nBase + rA)      * K + cg;
    const long gB1 = (long)(nBase + rA + 16) * K + cg;
    short* lA0 = sA + (w * 32) * 32;
    short* lA1 = sA + (w * 32 + 16) * 32;
    short* lB0 = sB + (w * 32) * 32;
    short* lB1 = sB + (w * 32 + 16) * 32;

    const int fr = lane & 15;
    const int csel = (((lane >> 4) ^ ((lane >> 1) & 3))) * 8;

    for (int kt = 0; kt < K / 32; ++kt) {
        const int k0 = kt * 32;
        __syncthreads();
        gld_lds16(A + gA0 + k0, lA0);
        gld_lds16(A + gA1 + k0, lA1);
        gld_lds16(BT + gB0 + k0, lB0);
        gld_lds16(BT + gB1 + k0, lB1);
        __syncthreads();
        short8 af[4], bf[4];
        #pragma unroll
        for (int i = 0; i < 4; ++i) {
            af[i] = *(const short8*)(sA + (mOff + i * 16 + fr) * 32 + csel);
            bf[i] = *(const short8*)(sB + (nOff + i * 16 + fr) * 32 + csel);
        }
        #pragma unroll
        for (int mi = 0; mi < 4; ++mi)
            #pragma unroll
            for (int ni = 0; ni < 4; ++ni)
                acc[mi][ni] = __builtin_amdgcn_mfma_f32_16x16x32_bf16(
                    af[mi], bf[ni], acc[mi][ni], 0, 0, 0);
    }

    // epilogue: D col = lane&15, row = (lane>>4)*4 + reg
    const int cn = lane & 15;
    const int cm = (lane >> 4) * 4;
    #pragma unroll
    for (int ni = 0; ni < 4; ++ni) {
        const int n = nBase + nOff + ni * 16 + cn;
        float bv = 0.f;
        if constexpr (EPI1) bv = bias[n];
        #pragma unroll
        for (int mi = 0; mi < 4; ++mi) {
            #pragma unroll
            for (int r = 0; r < 4; ++r) {
                const int m = mBase + mOff + mi * 16 + cm + r;
                if (m < N_NODES) {
                    if constexpr (EPI1) {
                        Obf[(size_t)m * N + n] = f2bf(fmaxf(acc[mi][ni][r] + bv, 0.f));
                    } else {
                        if (n < 128) Of0[(size_t)m * 128 + n] = acc[mi][ni][r];
                        else         Obf[(size_t)m * 128 + (n - 128)] = f2bf(acc[mi][ni][r]);
                    }
                }
            }
        }
    }
}

// ---------------------------------------------------------------- launch
extern "C" void kernel_launch(void* const* d_in, const int* in_sizes, int n_in,
                              void* d_out, int out_size, void* d_ws, size_t ws_size,
                              hipStream_t stream) {
    const float* feat   = (const float*)d_in[0];
    const int*   src    = (const int*)d_in[1];
    const int*   dst    = (const int*)d_in[2];
    const float* W1s    = (const float*)d_in[3];
    const float* W1n    = (const float*)d_in[4];
    const float* b1     = (const float*)d_in[5];
    const float* W2s    = (const float*)d_in[6];
    const float* W2n    = (const float*)d_in[7];
    const float* b2     = (const float*)d_in[8];
    const float* Wp1    = (const float*)d_in[9];
    const float* bp1    = (const float*)d_in[10];
    const float* Wp2    = (const float*)d_in[11];
    const float* bp2    = (const float*)d_in[12];
    float* out = (float*)d_out;

    char* w = (char*)d_ws;
    size_t off = 0;
    auto alloc = [&](size_t bytes) { char* p = w + off; off += (bytes + 255) & ~(size_t)255; return p; };
    int*   deg    = (int*)alloc(N_NODES * 4);
    int*   rowptr = (int*)alloc((N_NODES + 1) * 4);
    int*   cursor = (int*)alloc(N_NODES * 4);
    int*   col    = (int*)alloc(N_EDGES * 4);
    float* dinv   = (float*)alloc(N_NODES * 4);
    short* Abf    = (short*)alloc((size_t)N_NODES * 256 * 2);   // [feat|agg1] bf16
    short* W1T    = (short*)alloc((size_t)512 * 256 * 2);
    short* W2T    = (short*)alloc((size_t)256 * 512 * 2);
    short* h1bf   = (short*)alloc((size_t)N_NODES * 512 * 2);
    float* z      = (float*)alloc((size_t)N_NODES * 128 * 4);
    short* y1bf   = (short*)alloc((size_t)N_NODES * 128 * 2);

    hipMemsetAsync(deg, 0, N_NODES * 4, stream);
    k_deg<<<N_EDGES / 256, 256, 0, stream>>>(dst, deg);
    k_scan<<<1, 1024, 0, stream>>>(deg, rowptr, cursor, dinv);
    k_fill<<<N_EDGES / 256, 256, 0, stream>>>(src, dst, cursor, col);
    k_cvt_feat<<<(N_NODES * 32 + 255) / 256, 256, 0, stream>>>(feat, Abf);
    k_cvt_w<<<(512 * 256 + 256 * 512) / 256, 256, 0, stream>>>(W1s, W1n, W2s, W2n, W1T, W2T);
    k_agg<<<N_NODES, 128, 0, stream>>>(Abf, rowptr, col, dinv, Abf);
    dim3 g1((N_NODES + 127) / 128, 4);
    k_gemm_mfma<256, 512, true><<<g1, 256, 0, stream>>>(Abf, W1T, b1, h1bf, nullptr);
    dim3 g2((N_NODES + 127) / 128, 2);
    k_gemm_mfma<512, 256, false><<<g2, 256, 0, stream>>>(h1bf, W2T, nullptr, y1bf, z);
    k_aggmlp<<<N_NODES, 128, 0, stream>>>(y1bf, rowptr, col, dinv, z, b2,
                                          Wp1, bp1, Wp2, bp2, out);
}